// Round 2
// baseline (2585.439 us; speedup 1.0000x reference)
//
#include <hip/hip_runtime.h>
#include <hip/hip_bf16.h>

#define BATCH 2
#define SEQL 2048
#define NH 16
#define DH 64
#define DM 1024
#define ROWS 8

// ---------------------------------------------------------------------------
// Kernel 1: QKV projection.  grid = (B*S/ROWS, 3), block = 256.
// Each block: ROWS token rows, one of {Q,K,V}. Output layout [b,h,s,d].
// ---------------------------------------------------------------------------
__global__ __launch_bounds__(256) void qkv_kernel(
    const float* __restrict__ x,
    const float* __restrict__ Wq, const float* __restrict__ Wk, const float* __restrict__ Wv,
    const float* __restrict__ bq, const float* __restrict__ bk, const float* __restrict__ bv,
    float* __restrict__ q, float* __restrict__ k, float* __restrict__ v)
{
    __shared__ float xs[ROWS][DM];
    const int t = threadIdx.x;
    const int row0 = blockIdx.x * ROWS;       // flat (b*S+s) row
    const int which = blockIdx.y;             // 0=Q 1=K 2=V
    const float* W    = (which == 0) ? Wq : (which == 1) ? Wk : Wv;
    const float* bias = (which == 0) ? bq : (which == 1) ? bk : bv;
    float* out        = (which == 0) ? q  : (which == 1) ? k  : v;

    for (int i = t; i < ROWS * DM; i += 256)
        xs[i >> 10][i & (DM - 1)] = x[(size_t)row0 * DM + i];
    __syncthreads();

    const int d = t & 63;
    int base[4];
    float acc[ROWS][4];
    #pragma unroll
    for (int j = 0; j < 4; ++j) {
        const int o = t + 256 * j;            // output col in [0,1024): h*64+d
        const int h = o >> 6;
        base[j] = h * (DM * DH) + d;          // W[h][m][d] = W[h*65536 + m*64 + d]
        const float bb = bias[o];
        #pragma unroll
        for (int r = 0; r < ROWS; ++r) acc[r][j] = bb;
    }

    for (int m = 0; m < DM; ++m) {
        const int mo = m << 6;
        const float w0 = W[base[0] + mo];
        const float w1 = W[base[1] + mo];
        const float w2 = W[base[2] + mo];
        const float w3 = W[base[3] + mo];
        #pragma unroll
        for (int r = 0; r < ROWS; ++r) {
            const float xm = xs[r][m];
            acc[r][0] += xm * w0;
            acc[r][1] += xm * w1;
            acc[r][2] += xm * w2;
            acc[r][3] += xm * w3;
        }
    }

    #pragma unroll
    for (int r = 0; r < ROWS; ++r) {
        const int rIdx = row0 + r;
        const int b = rIdx >> 11;             // / SEQL
        const int s = rIdx & (SEQL - 1);
        #pragma unroll
        for (int j = 0; j < 4; ++j) {
            const int o = t + 256 * j;
            const int h = o >> 6;
            const size_t idx = (((size_t)(b * NH + h) * SEQL) + s) * DH + d;
            out[idx] = acc[r][j];
        }
    }
}

// ---------------------------------------------------------------------------
// Kernel 2: causal flash attention.  grid = (S/64, B*H), block = 256.
// One block per (b,h,Q-tile of 64 rows). Online softmax. z layout [b,s,h,d].
// ---------------------------------------------------------------------------
__global__ __launch_bounds__(256) void attn_kernel(
    const float* __restrict__ q, const float* __restrict__ k, const float* __restrict__ v,
    float* __restrict__ z)
{
    __shared__ float Qs[64][65];
    __shared__ float Ks[64][65];
    __shared__ float Vs[64][65];
    __shared__ float Ps[64][65];

    const int t  = threadIdx.x;
    const int bh = blockIdx.y;                // b*NH + h
    const int b  = bh >> 4;
    const int h  = bh & 15;
    const int qt = blockIdx.x;
    const int q0 = qt * 64;

    const size_t base = (size_t)bh * SEQL * DH;   // start of this (b,h) in [b,h,s,d]

    // Stage Q tile, pre-scaled by 1/sqrt(64)
    for (int i = t; i < 64 * DH; i += 256)
        Qs[i >> 6][i & 63] = q[base + (size_t)q0 * DH + i] * 0.125f;

    const int r  = t >> 2;                    // row in tile, 0..63
    const int cg = t & 3;                     // column group, 4 threads per row
    const int c0 = cg * 16;

    float m_i = -1e30f, l_i = 0.f;
    float o_acc[16];
    #pragma unroll
    for (int jj = 0; jj < 16; ++jj) o_acc[jj] = 0.f;

    for (int kt = 0; kt <= qt; ++kt) {
        __syncthreads();                      // prev PV done (also covers Qs staging)
        for (int i = t; i < 64 * DH; i += 256) {
            const size_t gk = base + (size_t)kt * 64 * DH + i;
            Ks[i >> 6][i & 63] = k[gk];
            Vs[i >> 6][i & 63] = v[gk];
        }
        __syncthreads();

        // scores: S[r][c0..c0+15] = Qs[r,:] . Ks[c,:]
        float sc[16];
        #pragma unroll
        for (int jj = 0; jj < 16; ++jj) sc[jj] = 0.f;
        for (int dd = 0; dd < DH; ++dd) {
            const float qd = Qs[r][dd];
            #pragma unroll
            for (int jj = 0; jj < 16; ++jj)
                sc[jj] += qd * Ks[c0 + jj][dd];
        }
        if (kt == qt) {                       // causal mask only on diagonal tile
            #pragma unroll
            for (int jj = 0; jj < 16; ++jj)
                if (c0 + jj > r) sc[jj] = -1e30f;
        }

        // online softmax over the row (4 threads per row)
        float mx = sc[0];
        #pragma unroll
        for (int jj = 1; jj < 16; ++jj) mx = fmaxf(mx, sc[jj]);
        mx = fmaxf(mx, __shfl_xor(mx, 1));
        mx = fmaxf(mx, __shfl_xor(mx, 2));
        const float m_new = fmaxf(m_i, mx);
        const float alpha = __expf(m_i - m_new);
        float lsum = 0.f;
        #pragma unroll
        for (int jj = 0; jj < 16; ++jj) {
            const float p = __expf(sc[jj] - m_new);
            Ps[r][c0 + jj] = p;
            lsum += p;
        }
        lsum += __shfl_xor(lsum, 1);
        lsum += __shfl_xor(lsum, 2);
        l_i = l_i * alpha + lsum;
        m_i = m_new;
        #pragma unroll
        for (int jj = 0; jj < 16; ++jj) o_acc[jj] *= alpha;
        __syncthreads();                      // Ps visible

        // PV: O[r][c0+jj] += sum_c P[r][c] * V[c][c0+jj]
        for (int c = 0; c < 64; ++c) {
            const float p = Ps[r][c];
            #pragma unroll
            for (int jj = 0; jj < 16; ++jj)
                o_acc[jj] += p * Vs[c][c0 + jj];
        }
    }

    const float inv = 1.f / l_i;
    const size_t zbase = (((size_t)b * SEQL + q0 + r) * NH + h) * DH;
    #pragma unroll
    for (int jj = 0; jj < 16; ++jj)
        z[zbase + c0 + jj] = o_acc[jj] * inv;
}

// ---------------------------------------------------------------------------
// Kernel 3: output projection. grid = B*S/ROWS, block = 256.
// z[b,s,:] (1024, contiguous) @ W_O reshaped [1024,1024] + b_O.
// ---------------------------------------------------------------------------
__global__ __launch_bounds__(256) void oproj_kernel(
    const float* __restrict__ zin, const float* __restrict__ Wo, const float* __restrict__ bo,
    float* __restrict__ out)
{
    __shared__ float zs[ROWS][DM];
    const int t = threadIdx.x;
    const int row0 = blockIdx.x * ROWS;
    for (int i = t; i < ROWS * DM; i += 256)
        zs[i >> 10][i & (DM - 1)] = zin[(size_t)row0 * DM + i];
    __syncthreads();

    float acc[ROWS][4];
    #pragma unroll
    for (int j = 0; j < 4; ++j) {
        const float bb = bo[t + 256 * j];
        #pragma unroll
        for (int r = 0; r < ROWS; ++r) acc[r][j] = bb;
    }

    for (int m = 0; m < DM; ++m) {
        const float* wrow = Wo + (size_t)m * DM + t;   // W_O[h,d,m'] flat = [(h*64+d)*1024 + m']
        const float w0 = wrow[0];
        const float w1 = wrow[256];
        const float w2 = wrow[512];
        const float w3 = wrow[768];
        #pragma unroll
        for (int r = 0; r < ROWS; ++r) {
            const float zm = zs[r][m];
            acc[r][0] += zm * w0;
            acc[r][1] += zm * w1;
            acc[r][2] += zm * w2;
            acc[r][3] += zm * w3;
        }
    }

    #pragma unroll
    for (int r = 0; r < ROWS; ++r) {
        #pragma unroll
        for (int j = 0; j < 4; ++j)
            out[(size_t)(row0 + r) * DM + t + 256 * j] = acc[r][j];
    }
}

// ---------------------------------------------------------------------------
extern "C" void kernel_launch(void* const* d_in, const int* in_sizes, int n_in,
                              void* d_out, int out_size, void* d_ws, size_t ws_size,
                              hipStream_t stream)
{
    const float* x  = (const float*)d_in[0];
    const float* Wq = (const float*)d_in[1];
    const float* Wk = (const float*)d_in[2];
    const float* Wv = (const float*)d_in[3];
    const float* Wo = (const float*)d_in[4];
    const float* bq = (const float*)d_in[5];
    const float* bk = (const float*)d_in[6];
    const float* bv = (const float*)d_in[7];
    const float* bo = (const float*)d_in[8];
    float* out = (float*)d_out;

    const size_t QKV = (size_t)BATCH * SEQL * NH * DH;   // 4,194,304 elems
    float* q = (float*)d_ws;
    float* k = q + QKV;
    float* v = k + QKV;
    float* z = v + QKV;                                  // total ws use: 64 MB

    qkv_kernel<<<dim3(BATCH * SEQL / ROWS, 3), 256, 0, stream>>>(
        x, Wq, Wk, Wv, bq, bk, bv, q, k, v);
    attn_kernel<<<dim3(SEQL / 64, BATCH * NH), 256, 0, stream>>>(q, k, v, z);
    oproj_kernel<<<dim3(BATCH * SEQL / ROWS), 256, 0, stream>>>(z, Wo, bo, out);
}

// Round 3
// 757.690 us; speedup vs baseline: 3.4123x; 3.4123x over previous
//
#include <hip/hip_runtime.h>
#include <hip/hip_bf16.h>

#define BATCH 2
#define SEQL 2048
#define NH 16
#define DH 64
#define DM 1024
#define ROWS 8
#define LDK 72   // K-tile LDS row stride in bf16 (64 + 8 pad -> 144B rows, 16B aligned)

typedef __hip_bfloat16 bf16;
typedef __attribute__((ext_vector_type(8))) short  bf16x8;
typedef __attribute__((ext_vector_type(4))) float  f32x4;

// ---------------------------------------------------------------------------
// Kernel 1: QKV projection (fp32 math, bf16 outputs for MFMA attention).
// grid = (B*S/ROWS, 3), block = 256. Output layout [b,h,s,d].
// ---------------------------------------------------------------------------
__global__ __launch_bounds__(256) void qkv_kernel(
    const float* __restrict__ x,
    const float* __restrict__ Wq, const float* __restrict__ Wk, const float* __restrict__ Wv,
    const float* __restrict__ bq, const float* __restrict__ bk, const float* __restrict__ bv,
    bf16* __restrict__ q, bf16* __restrict__ k, bf16* __restrict__ v)
{
    __shared__ float xs[ROWS][DM];
    const int t = threadIdx.x;
    const int row0 = blockIdx.x * ROWS;
    const int which = blockIdx.y;
    const float* W    = (which == 0) ? Wq : (which == 1) ? Wk : Wv;
    const float* bias = (which == 0) ? bq : (which == 1) ? bk : bv;
    bf16* out         = (which == 0) ? q  : (which == 1) ? k  : v;

    for (int i = t; i < ROWS * DM; i += 256)
        xs[i >> 10][i & (DM - 1)] = x[(size_t)row0 * DM + i];
    __syncthreads();

    const int d = t & 63;
    int base[4];
    float acc[ROWS][4];
    #pragma unroll
    for (int j = 0; j < 4; ++j) {
        const int o = t + 256 * j;
        const int h = o >> 6;
        base[j] = h * (DM * DH) + d;
        const float bb = bias[o];
        #pragma unroll
        for (int r = 0; r < ROWS; ++r) acc[r][j] = bb;
    }

    for (int m = 0; m < DM; ++m) {
        const int mo = m << 6;
        const float w0 = W[base[0] + mo];
        const float w1 = W[base[1] + mo];
        const float w2 = W[base[2] + mo];
        const float w3 = W[base[3] + mo];
        #pragma unroll
        for (int r = 0; r < ROWS; ++r) {
            const float xm = xs[r][m];
            acc[r][0] += xm * w0;
            acc[r][1] += xm * w1;
            acc[r][2] += xm * w2;
            acc[r][3] += xm * w3;
        }
    }

    #pragma unroll
    for (int r = 0; r < ROWS; ++r) {
        const int rIdx = row0 + r;
        const int b = rIdx >> 11;
        const int s = rIdx & (SEQL - 1);
        #pragma unroll
        for (int j = 0; j < 4; ++j) {
            const int o = t + 256 * j;
            const int h = o >> 6;
            const size_t idx = (((size_t)(b * NH + h) * SEQL) + s) * DH + d;
            out[idx] = __float2bfloat16(acc[r][j]);
        }
    }
}

// ---------------------------------------------------------------------------
// Kernel 2: MFMA flash attention (causal). grid = (bh=32, qt=32), block = 256.
// Block handles 64 Q rows (qt = 31 - blockIdx.y so heavy blocks launch first).
// Wave w -> 16 Q rows. mfma_f32_16x16x32_bf16.
//   A-frag: A[m=lane&15][k=quad*8+j]   B-frag: B[k=quad*8+j][n=lane&15]
//   C/D:    row = quad*4+reg, col = lane&15
// K tile row-major (stride LDK). V tile pair-packed transposed with XOR
// swizzle: Vt2[d][p] = (V[2p][d], V[2p+1][d]), phys_p = p ^ sw(d),
// sw(d) = ((d&7) ^ ((d>>3)&7)) << 2  -> b128 reads/writes bank-balanced.
// ---------------------------------------------------------------------------
__global__ __launch_bounds__(256) void attn_kernel(
    const bf16* __restrict__ qg, const bf16* __restrict__ kg, const bf16* __restrict__ vg,
    float* __restrict__ z)
{
    __shared__ bf16     KsS[64 * LDK];        // 9216 B
    __shared__ unsigned VtS[64 * 32];         // 8192 B (swizzled dwords)
    __shared__ bf16     PsS[4][16 * LDK];     // 9216 B (per-wave P tiles)

    const int t    = threadIdx.x;
    const int lane = t & 63;
    const int w    = t >> 6;                  // wave 0..3
    const int m    = lane & 15;
    const int quad = lane >> 4;

    const int bh = blockIdx.x;                // b*NH + h
    const int b  = bh >> 4;
    const int h  = bh & 15;
    const int qt = (gridDim.y - 1) - blockIdx.y;
    const int q0 = qt * 64;

    const size_t base = (size_t)bh * SEQL * DH;

    // staging task split: thread -> (row-pair rp, d-chunk a8)
    const int rp = t >> 3;                    // 0..31
    const int a8 = t & 7;                     // 0..7
    const int d0 = a8 * 8;

    // Q fragments in registers (wave's 16 rows), one per k-step
    bf16x8 aq[2];
    {
        const bf16* qp = qg + base + (size_t)(q0 + w * 16 + m) * DH + quad * 8;
        aq[0] = *(const bf16x8*)(qp);
        aq[1] = *(const bf16x8*)(qp + 32);
    }

    f32x4 zacc[4];
    #pragma unroll
    for (int nt = 0; nt < 4; ++nt) zacc[nt] = (f32x4){0.f, 0.f, 0.f, 0.f};
    float m_i[4] = {-1e30f, -1e30f, -1e30f, -1e30f};
    float l_i[4] = {0.f, 0.f, 0.f, 0.f};

    bf16* Psw = PsS[w];

    for (int kt = 0; kt <= qt; ++kt) {
        __syncthreads();                      // all waves done with prev K/V
        // ---- stage K and V tiles ----
        {
            const bf16* kr = kg + base + (size_t)(kt * 64 + 2 * rp) * DH + d0;
            const bf16* vr = vg + base + (size_t)(kt * 64 + 2 * rp) * DH + d0;
            const uint4 k0 = *(const uint4*)(kr);
            const uint4 k1 = *(const uint4*)(kr + DH);
            const uint4 v0 = *(const uint4*)(vr);
            const uint4 v1 = *(const uint4*)(vr + DH);
            *(uint4*)(&KsS[(2 * rp) * LDK + d0])     = k0;
            *(uint4*)(&KsS[(2 * rp + 1) * LDK + d0]) = k1;
            const unsigned short* h0 = (const unsigned short*)&v0;
            const unsigned short* h1 = (const unsigned short*)&v1;
            #pragma unroll
            for (int j = 0; j < 8; ++j) {
                const unsigned pw = (unsigned)h0[j] | ((unsigned)h1[j] << 16);
                VtS[(d0 + j) * 32 + (rp ^ ((j ^ a8) << 2))] = pw;
            }
        }
        __syncthreads();

        // ---- S = Q K^T (16x64 per wave) ----
        f32x4 sc[4];
        #pragma unroll
        for (int nt = 0; nt < 4; ++nt) sc[nt] = (f32x4){0.f, 0.f, 0.f, 0.f};
        #pragma unroll
        for (int ks = 0; ks < 2; ++ks) {
            #pragma unroll
            for (int nt = 0; nt < 4; ++nt) {
                const bf16x8 bk = *(const bf16x8*)(&KsS[(nt * 16 + m) * LDK + ks * 32 + quad * 8]);
                sc[nt] = __builtin_amdgcn_mfma_f32_16x16x32_bf16(aq[ks], bk, sc[nt], 0, 0, 0);
            }
        }
        // scale
        #pragma unroll
        for (int nt = 0; nt < 4; ++nt)
            #pragma unroll
            for (int rg = 0; rg < 4; ++rg) sc[nt][rg] *= 0.125f;
        // causal mask (diagonal tile only)
        if (kt == qt) {
            #pragma unroll
            for (int nt = 0; nt < 4; ++nt) {
                const int col = nt * 16 + m;
                #pragma unroll
                for (int rg = 0; rg < 4; ++rg) {
                    const int row = w * 16 + quad * 4 + rg;
                    if (col > row) sc[nt][rg] = -1e30f;
                }
            }
        }

        // ---- online softmax (per row = per reg, reduce across 16 lanes) ----
        #pragma unroll
        for (int rg = 0; rg < 4; ++rg) {
            float mx = fmaxf(fmaxf(sc[0][rg], sc[1][rg]), fmaxf(sc[2][rg], sc[3][rg]));
            mx = fmaxf(mx, __shfl_xor(mx, 1));
            mx = fmaxf(mx, __shfl_xor(mx, 2));
            mx = fmaxf(mx, __shfl_xor(mx, 4));
            mx = fmaxf(mx, __shfl_xor(mx, 8));
            const float mn = fmaxf(m_i[rg], mx);
            const float al = __expf(m_i[rg] - mn);
            m_i[rg] = mn;
            float rs = 0.f;
            #pragma unroll
            for (int nt = 0; nt < 4; ++nt) {
                const float p = __expf(sc[nt][rg] - mn);
                Psw[(quad * 4 + rg) * LDK + nt * 16 + m] = __float2bfloat16(p);
                rs += p;
            }
            rs += __shfl_xor(rs, 1);
            rs += __shfl_xor(rs, 2);
            rs += __shfl_xor(rs, 4);
            rs += __shfl_xor(rs, 8);
            l_i[rg] = l_i[rg] * al + rs;
            #pragma unroll
            for (int nt = 0; nt < 4; ++nt) zacc[nt][rg] *= al;
        }
        // (wave-private LDS RAW: DS pipe is in-order per wave; compiler waits lgkmcnt)

        // ---- Z += P V ----
        #pragma unroll
        for (int ks = 0; ks < 2; ++ks) {
            const bf16x8 ap = *(const bf16x8*)(&Psw[m * LDK + ks * 32 + quad * 8]);
            #pragma unroll
            for (int nt = 0; nt < 4; ++nt) {
                const int n  = nt * 16 + m;
                const int p0 = ks * 16 + quad * 4;
                const int sw = ((n & 7) ^ ((n >> 3) & 7)) << 2;
                const bf16x8 bv = *(const bf16x8*)(&VtS[n * 32 + (p0 ^ sw)]);
                zacc[nt] = __builtin_amdgcn_mfma_f32_16x16x32_bf16(ap, bv, zacc[nt], 0, 0, 0);
            }
        }
    }

    // ---- epilogue: z[b, s, h, d] fp32 ----
    float invl[4];
    #pragma unroll
    for (int rg = 0; rg < 4; ++rg) invl[rg] = 1.f / l_i[rg];
    #pragma unroll
    for (int nt = 0; nt < 4; ++nt) {
        const int d = nt * 16 + m;
        #pragma unroll
        for (int rg = 0; rg < 4; ++rg) {
            const int qrow = q0 + w * 16 + quad * 4 + rg;
            z[(((size_t)b * SEQL + qrow) * NH + h) * DH + d] = zacc[nt][rg] * invl[rg];
        }
    }
}

// ---------------------------------------------------------------------------
// Kernel 3: output projection (unchanged). grid = B*S/ROWS, block = 256.
// ---------------------------------------------------------------------------
__global__ __launch_bounds__(256) void oproj_kernel(
    const float* __restrict__ zin, const float* __restrict__ Wo, const float* __restrict__ bo,
    float* __restrict__ out)
{
    __shared__ float zs[ROWS][DM];
    const int t = threadIdx.x;
    const int row0 = blockIdx.x * ROWS;
    for (int i = t; i < ROWS * DM; i += 256)
        zs[i >> 10][i & (DM - 1)] = zin[(size_t)row0 * DM + i];
    __syncthreads();

    float acc[ROWS][4];
    #pragma unroll
    for (int j = 0; j < 4; ++j) {
        const float bb = bo[t + 256 * j];
        #pragma unroll
        for (int r = 0; r < ROWS; ++r) acc[r][j] = bb;
    }

    for (int m = 0; m < DM; ++m) {
        const float* wrow = Wo + (size_t)m * DM + t;
        const float w0 = wrow[0];
        const float w1 = wrow[256];
        const float w2 = wrow[512];
        const float w3 = wrow[768];
        #pragma unroll
        for (int r = 0; r < ROWS; ++r) {
            const float zm = zs[r][m];
            acc[r][0] += zm * w0;
            acc[r][1] += zm * w1;
            acc[r][2] += zm * w2;
            acc[r][3] += zm * w3;
        }
    }

    #pragma unroll
    for (int r = 0; r < ROWS; ++r) {
        #pragma unroll
        for (int j = 0; j < 4; ++j)
            out[(size_t)(row0 + r) * DM + t + 256 * j] = acc[r][j];
    }
}

// ---------------------------------------------------------------------------
extern "C" void kernel_launch(void* const* d_in, const int* in_sizes, int n_in,
                              void* d_out, int out_size, void* d_ws, size_t ws_size,
                              hipStream_t stream)
{
    const float* x  = (const float*)d_in[0];
    const float* Wq = (const float*)d_in[1];
    const float* Wk = (const float*)d_in[2];
    const float* Wv = (const float*)d_in[3];
    const float* Wo = (const float*)d_in[4];
    const float* bq = (const float*)d_in[5];
    const float* bk = (const float*)d_in[6];
    const float* bv = (const float*)d_in[7];
    const float* bo = (const float*)d_in[8];
    float* out = (float*)d_out;

    const size_t QKV = (size_t)BATCH * SEQL * NH * DH;   // 4,194,304 elems
    bf16* q = (bf16*)d_ws;
    bf16* k = q + QKV;
    bf16* v = k + QKV;
    float* z = (float*)(v + QKV);                        // 24 MB bf16 + 16 MB fp32

    qkv_kernel<<<dim3(BATCH * SEQL / ROWS, 3), 256, 0, stream>>>(
        x, Wq, Wk, Wv, bq, bk, bv, q, k, v);
    attn_kernel<<<dim3(BATCH * NH, SEQL / 64), 256, 0, stream>>>(q, k, v, z);
    oproj_kernel<<<dim3(BATCH * SEQL / ROWS), 256, 0, stream>>>(z, Wo, bo, out);
}

// Round 4
// 210.226 us; speedup vs baseline: 12.2984x; 3.6042x over previous
//
#include <hip/hip_runtime.h>
#include <hip/hip_bf16.h>

#define BATCH 2
#define SEQL 2048
#define NH 16
#define DH 64
#define DM 1024
#define LDK 72   // K-tile LDS row stride in bf16 (attn kernel)

typedef __hip_bfloat16 bf16;
typedef __attribute__((ext_vector_type(8))) short  bf16x8;
typedef __attribute__((ext_vector_type(4))) float  f32x4;

__device__ __forceinline__ void gl_lds16(const void* g, void* l) {
    __builtin_amdgcn_global_load_lds(
        (const __attribute__((address_space(1))) unsigned int*)g,
        (__attribute__((address_space(3))) unsigned int*)l, 16, 0, 0);
}

// ---------------------------------------------------------------------------
// Prep A: x (fp32, [4096,1024]) -> bf16. grid 4096 x 256, 4 elems/thread.
// ---------------------------------------------------------------------------
__global__ __launch_bounds__(256) void xconv_kernel(
    const float* __restrict__ x, bf16* __restrict__ xb)
{
    const size_t i = ((size_t)blockIdx.x * 256 + threadIdx.x) * 4;
    const float4 v = *(const float4*)(x + i);
    bf16 o[4];
    o[0] = __float2bfloat16(v.x); o[1] = __float2bfloat16(v.y);
    o[2] = __float2bfloat16(v.z); o[3] = __float2bfloat16(v.w);
    *(uint2*)(xb + i) = *(const uint2*)o;
}

// ---------------------------------------------------------------------------
// Prep B: weights -> transposed bf16 Bt[n][k] (4 matrices of [1024][1024]).
// z<3: source S[m][c] = W[h(c)][m][d(c)] (c head-aligned per 64-tile).
// z=3: source S[hd][m'] = W_O flat. Output Bt[c][m] / Bt[m'][hd].
// grid (16,16,4), block 256.
// ---------------------------------------------------------------------------
__global__ __launch_bounds__(256) void wtrans_kernel(
    const float* __restrict__ Wq, const float* __restrict__ Wk,
    const float* __restrict__ Wv, const float* __restrict__ Wo,
    bf16* __restrict__ Wt)
{
    __shared__ float ts[64][65];
    const int zi = blockIdx.z;
    const float* src = (zi == 0) ? Wq : (zi == 1) ? Wk : (zi == 2) ? Wv : Wo;
    bf16* dst = Wt + (size_t)zi * DM * DM;
    const int row0 = blockIdx.y * 64;
    const int col0 = blockIdx.x * 64;
    const int tx = threadIdx.x & 63;
    const int ty = threadIdx.x >> 6;

    if (zi < 3) {
        const int h = col0 >> 6;
        #pragma unroll
        for (int i = 0; i < 16; ++i) {
            const int r = ty + 4 * i;
            ts[r][tx] = src[h * (DM * DH) + (row0 + r) * DH + tx];
        }
    } else {
        #pragma unroll
        for (int i = 0; i < 16; ++i) {
            const int r = ty + 4 * i;
            ts[r][tx] = src[(size_t)(row0 + r) * DM + col0 + tx];
        }
    }
    __syncthreads();
    #pragma unroll
    for (int i = 0; i < 16; ++i) {
        const int rr = ty + 4 * i;
        dst[(size_t)(col0 + rr) * DM + row0 + tx] = __float2bfloat16(ts[tx][rr]);
    }
}

// ---------------------------------------------------------------------------
// QKV GEMM (m97 structure): C[4096x1024] = xb @ Bt^T, scatter to [b,h,s,d] bf16.
// grid (8, 32, 3), block 256 (4 waves, each 64x64).
// ---------------------------------------------------------------------------
__global__ __launch_bounds__(256) void qkv_gemm(
    const bf16* __restrict__ xb, const bf16* __restrict__ Wt,
    const float* __restrict__ bq, const float* __restrict__ bk, const float* __restrict__ bv,
    bf16* __restrict__ qkv)
{
    __shared__ __align__(16) bf16 As[128 * 32];
    __shared__ __align__(16) bf16 Bs[128 * 32];

    const int t = threadIdx.x;
    const int lane = t & 63, w = t >> 6;
    const int ml = lane & 15, quad = lane >> 4;
    const int wr = w >> 1, wc = w & 1;
    const int bn = blockIdx.x, bm = blockIdx.y, which = blockIdx.z;

    const bf16* A0 = xb + (size_t)(bm * 128) * DM;
    const bf16* B0 = Wt + (size_t)which * DM * DM + (size_t)(bn * 128) * DM;
    const float* bias = (which == 0) ? bq : (which == 1) ? bk : bv;
    bf16* outb = qkv + (size_t)which * (BATCH * SEQL * NH * DH);

    f32x4 acc[4][4];
    #pragma unroll
    for (int i = 0; i < 4; ++i)
        #pragma unroll
        for (int j = 0; j < 4; ++j) acc[i][j] = (f32x4){0.f, 0.f, 0.f, 0.f};

    for (int kt = 0; kt < DM / 32; ++kt) {
        const int k0 = kt * 32;
        __syncthreads();
        #pragma unroll
        for (int j = 0; j < 2; ++j) {
            const int flat = t + j * 256;
            const int r = flat >> 2, c = (flat & 3) * 8;
            gl_lds16(A0 + (size_t)r * DM + k0 + c, &As[flat * 8]);
            gl_lds16(B0 + (size_t)r * DM + k0 + c, &Bs[flat * 8]);
        }
        __syncthreads();
        bf16x8 af[4], bfr[4];
        #pragma unroll
        for (int i = 0; i < 4; ++i)
            af[i] = *(const bf16x8*)&As[(wr * 64 + i * 16 + ml) * 32 + quad * 8];
        #pragma unroll
        for (int j = 0; j < 4; ++j)
            bfr[j] = *(const bf16x8*)&Bs[(wc * 64 + j * 16 + ml) * 32 + quad * 8];
        #pragma unroll
        for (int i = 0; i < 4; ++i)
            #pragma unroll
            for (int j = 0; j < 4; ++j)
                acc[i][j] = __builtin_amdgcn_mfma_f32_16x16x32_bf16(af[i], bfr[j], acc[i][j], 0, 0, 0);
    }

    float bb[4];
    #pragma unroll
    for (int j = 0; j < 4; ++j) bb[j] = bias[bn * 128 + wc * 64 + j * 16 + ml];

    #pragma unroll
    for (int i = 0; i < 4; ++i) {
        #pragma unroll
        for (int rg = 0; rg < 4; ++rg) {
            const int row = bm * 128 + wr * 64 + i * 16 + quad * 4 + rg;
            const int b = row >> 11;
            const int s = row & (SEQL - 1);
            #pragma unroll
            for (int j = 0; j < 4; ++j) {
                const int col = bn * 128 + wc * 64 + j * 16 + ml;
                const int h = col >> 6, d = col & 63;
                outb[(((size_t)(b * NH + h)) * SEQL + s) * DH + d] =
                    __float2bfloat16(acc[i][j][rg] + bb[j]);
            }
        }
    }
}

// ---------------------------------------------------------------------------
// O-proj GEMM: out[4096x1024] fp32 = zb @ Bt_o^T + b_O. grid (8,32), block 256.
// ---------------------------------------------------------------------------
__global__ __launch_bounds__(256) void oproj_gemm(
    const bf16* __restrict__ zb, const bf16* __restrict__ Bt,
    const float* __restrict__ bo, float* __restrict__ out)
{
    __shared__ __align__(16) bf16 As[128 * 32];
    __shared__ __align__(16) bf16 Bs[128 * 32];

    const int t = threadIdx.x;
    const int lane = t & 63, w = t >> 6;
    const int ml = lane & 15, quad = lane >> 4;
    const int wr = w >> 1, wc = w & 1;
    const int bn = blockIdx.x, bm = blockIdx.y;

    const bf16* A0 = zb + (size_t)(bm * 128) * DM;
    const bf16* B0 = Bt + (size_t)(bn * 128) * DM;

    f32x4 acc[4][4];
    #pragma unroll
    for (int i = 0; i < 4; ++i)
        #pragma unroll
        for (int j = 0; j < 4; ++j) acc[i][j] = (f32x4){0.f, 0.f, 0.f, 0.f};

    for (int kt = 0; kt < DM / 32; ++kt) {
        const int k0 = kt * 32;
        __syncthreads();
        #pragma unroll
        for (int j = 0; j < 2; ++j) {
            const int flat = t + j * 256;
            const int r = flat >> 2, c = (flat & 3) * 8;
            gl_lds16(A0 + (size_t)r * DM + k0 + c, &As[flat * 8]);
            gl_lds16(B0 + (size_t)r * DM + k0 + c, &Bs[flat * 8]);
        }
        __syncthreads();
        bf16x8 af[4], bfr[4];
        #pragma unroll
        for (int i = 0; i < 4; ++i)
            af[i] = *(const bf16x8*)&As[(wr * 64 + i * 16 + ml) * 32 + quad * 8];
        #pragma unroll
        for (int j = 0; j < 4; ++j)
            bfr[j] = *(const bf16x8*)&Bs[(wc * 64 + j * 16 + ml) * 32 + quad * 8];
        #pragma unroll
        for (int i = 0; i < 4; ++i)
            #pragma unroll
            for (int j = 0; j < 4; ++j)
                acc[i][j] = __builtin_amdgcn_mfma_f32_16x16x32_bf16(af[i], bfr[j], acc[i][j], 0, 0, 0);
    }

    float bb[4];
    #pragma unroll
    for (int j = 0; j < 4; ++j) bb[j] = bo[bn * 128 + wc * 64 + j * 16 + ml];

    #pragma unroll
    for (int i = 0; i < 4; ++i) {
        #pragma unroll
        for (int rg = 0; rg < 4; ++rg) {
            const int row = bm * 128 + wr * 64 + i * 16 + quad * 4 + rg;
            #pragma unroll
            for (int j = 0; j < 4; ++j) {
                const int col = bn * 128 + wc * 64 + j * 16 + ml;
                out[(size_t)row * DM + col] = acc[i][j][rg] + bb[j];
            }
        }
    }
}

// ---------------------------------------------------------------------------
// MFMA flash attention (causal), unchanged except z output is bf16.
// grid = (bh=32, qt=32), block = 256.
// ---------------------------------------------------------------------------
__global__ __launch_bounds__(256) void attn_kernel(
    const bf16* __restrict__ qg, const bf16* __restrict__ kg, const bf16* __restrict__ vg,
    bf16* __restrict__ z)
{
    __shared__ bf16     KsS[64 * LDK];
    __shared__ unsigned VtS[64 * 32];
    __shared__ bf16     PsS[4][16 * LDK];

    const int t    = threadIdx.x;
    const int lane = t & 63;
    const int w    = t >> 6;
    const int m    = lane & 15;
    const int quad = lane >> 4;

    const int bh = blockIdx.x;
    const int b  = bh >> 4;
    const int h  = bh & 15;
    const int qt = (gridDim.y - 1) - blockIdx.y;
    const int q0 = qt * 64;

    const size_t base = (size_t)bh * SEQL * DH;

    const int rp = t >> 3;
    const int a8 = t & 7;
    const int d0 = a8 * 8;

    bf16x8 aq[2];
    {
        const bf16* qp = qg + base + (size_t)(q0 + w * 16 + m) * DH + quad * 8;
        aq[0] = *(const bf16x8*)(qp);
        aq[1] = *(const bf16x8*)(qp + 32);
    }

    f32x4 zacc[4];
    #pragma unroll
    for (int nt = 0; nt < 4; ++nt) zacc[nt] = (f32x4){0.f, 0.f, 0.f, 0.f};
    float m_i[4] = {-1e30f, -1e30f, -1e30f, -1e30f};
    float l_i[4] = {0.f, 0.f, 0.f, 0.f};

    bf16* Psw = PsS[w];

    for (int kt = 0; kt <= qt; ++kt) {
        __syncthreads();
        {
            const bf16* kr = kg + base + (size_t)(kt * 64 + 2 * rp) * DH + d0;
            const bf16* vr = vg + base + (size_t)(kt * 64 + 2 * rp) * DH + d0;
            const uint4 k0 = *(const uint4*)(kr);
            const uint4 k1 = *(const uint4*)(kr + DH);
            const uint4 v0 = *(const uint4*)(vr);
            const uint4 v1 = *(const uint4*)(vr + DH);
            *(uint4*)(&KsS[(2 * rp) * LDK + d0])     = k0;
            *(uint4*)(&KsS[(2 * rp + 1) * LDK + d0]) = k1;
            const unsigned short* h0 = (const unsigned short*)&v0;
            const unsigned short* h1 = (const unsigned short*)&v1;
            #pragma unroll
            for (int j = 0; j < 8; ++j) {
                const unsigned pw = (unsigned)h0[j] | ((unsigned)h1[j] << 16);
                VtS[(d0 + j) * 32 + (rp ^ ((j ^ a8) << 2))] = pw;
            }
        }
        __syncthreads();

        f32x4 sc[4];
        #pragma unroll
        for (int nt = 0; nt < 4; ++nt) sc[nt] = (f32x4){0.f, 0.f, 0.f, 0.f};
        #pragma unroll
        for (int ks = 0; ks < 2; ++ks) {
            #pragma unroll
            for (int nt = 0; nt < 4; ++nt) {
                const bf16x8 bk = *(const bf16x8*)(&KsS[(nt * 16 + m) * LDK + ks * 32 + quad * 8]);
                sc[nt] = __builtin_amdgcn_mfma_f32_16x16x32_bf16(aq[ks], bk, sc[nt], 0, 0, 0);
            }
        }
        #pragma unroll
        for (int nt = 0; nt < 4; ++nt)
            #pragma unroll
            for (int rg = 0; rg < 4; ++rg) sc[nt][rg] *= 0.125f;
        if (kt == qt) {
            #pragma unroll
            for (int nt = 0; nt < 4; ++nt) {
                const int col = nt * 16 + m;
                #pragma unroll
                for (int rg = 0; rg < 4; ++rg) {
                    const int row = w * 16 + quad * 4 + rg;
                    if (col > row) sc[nt][rg] = -1e30f;
                }
            }
        }

        #pragma unroll
        for (int rg = 0; rg < 4; ++rg) {
            float mx = fmaxf(fmaxf(sc[0][rg], sc[1][rg]), fmaxf(sc[2][rg], sc[3][rg]));
            mx = fmaxf(mx, __shfl_xor(mx, 1));
            mx = fmaxf(mx, __shfl_xor(mx, 2));
            mx = fmaxf(mx, __shfl_xor(mx, 4));
            mx = fmaxf(mx, __shfl_xor(mx, 8));
            const float mn = fmaxf(m_i[rg], mx);
            const float al = __expf(m_i[rg] - mn);
            m_i[rg] = mn;
            float rs = 0.f;
            #pragma unroll
            for (int nt = 0; nt < 4; ++nt) {
                const float p = __expf(sc[nt][rg] - mn);
                Psw[(quad * 4 + rg) * LDK + nt * 16 + m] = __float2bfloat16(p);
                rs += p;
            }
            rs += __shfl_xor(rs, 1);
            rs += __shfl_xor(rs, 2);
            rs += __shfl_xor(rs, 4);
            rs += __shfl_xor(rs, 8);
            l_i[rg] = l_i[rg] * al + rs;
            #pragma unroll
            for (int nt = 0; nt < 4; ++nt) zacc[nt][rg] *= al;
        }

        #pragma unroll
        for (int ks = 0; ks < 2; ++ks) {
            const bf16x8 ap = *(const bf16x8*)(&Psw[m * LDK + ks * 32 + quad * 8]);
            #pragma unroll
            for (int nt = 0; nt < 4; ++nt) {
                const int n  = nt * 16 + m;
                const int p0 = ks * 16 + quad * 4;
                const int sw = ((n & 7) ^ ((n >> 3) & 7)) << 2;
                const bf16x8 bv = *(const bf16x8*)(&VtS[n * 32 + (p0 ^ sw)]);
                zacc[nt] = __builtin_amdgcn_mfma_f32_16x16x32_bf16(ap, bv, zacc[nt], 0, 0, 0);
            }
        }
    }

    float invl[4];
    #pragma unroll
    for (int rg = 0; rg < 4; ++rg) invl[rg] = 1.f / l_i[rg];
    #pragma unroll
    for (int nt = 0; nt < 4; ++nt) {
        const int d = nt * 16 + m;
        #pragma unroll
        for (int rg = 0; rg < 4; ++rg) {
            const int qrow = q0 + w * 16 + quad * 4 + rg;
            z[(((size_t)b * SEQL + qrow) * NH + h) * DH + d] =
                __float2bfloat16(zacc[nt][rg] * invl[rg]);
        }
    }
}

// ---------------------------------------------------------------------------
extern "C" void kernel_launch(void* const* d_in, const int* in_sizes, int n_in,
                              void* d_out, int out_size, void* d_ws, size_t ws_size,
                              hipStream_t stream)
{
    const float* x  = (const float*)d_in[0];
    const float* Wq = (const float*)d_in[1];
    const float* Wk = (const float*)d_in[2];
    const float* Wv = (const float*)d_in[3];
    const float* Wo = (const float*)d_in[4];
    const float* bq = (const float*)d_in[5];
    const float* bk = (const float*)d_in[6];
    const float* bv = (const float*)d_in[7];
    const float* bo = (const float*)d_in[8];
    float* out = (float*)d_out;

    const size_t TOK = (size_t)BATCH * SEQL;             // 4096
    const size_t QKV = TOK * DM;                         // 4M elems
    bf16* xb  = (bf16*)d_ws;                             // 4M
    bf16* Wt  = xb + QKV;                                // 4 x 1M
    bf16* qkv = Wt + 4 * (size_t)DM * DM;                // 3 x 4M
    bf16* zb  = qkv + 3 * QKV;                           // 4M   (48 MB total)

    xconv_kernel<<<dim3(TOK * DM / 1024), 256, 0, stream>>>(x, xb);
    wtrans_kernel<<<dim3(16, 16, 4), 256, 0, stream>>>(Wq, Wk, Wv, Wo, Wt);
    qkv_gemm<<<dim3(8, 32, 3), 256, 0, stream>>>(xb, Wt, bq, bk, bv, qkv);
    attn_kernel<<<dim3(BATCH * NH, SEQL / 64), 256, 0, stream>>>(
        qkv, qkv + QKV, qkv + 2 * QKV, zb);
    oproj_gemm<<<dim3(8, 32), 256, 0, stream>>>(zb, Wt + 3 * (size_t)DM * DM, bo, out);
}